// Round 1
// baseline (3338.854 us; speedup 1.0000x reference)
//
#include <hip/hip_runtime.h>
#include <hip/hip_bf16.h>
#include <math.h>

// ---------------------------------------------------------------------------
// HyenaAttention: out = ((v*g0) ⊛ h0 * g1) ⊛ h1 @ W_out   (⊛ = circular filter)
//   B=4, N=4096, D=1024, ORDER=2, fft_len = N = 4096 (power of 2, no padding)
// Round 1: correctness-first full-f32 path.
//   - 5 tiled f32 GEMMs (M=16384, K=1024, N=1024), gate GEMMs fuse
//     sigmoid*multiply epilogue in-place.
//   - FFT filter kernel: per (b,d) column, DIF fwd FFT -> pointwise H
//     (bit-reversed index, Hermitian-extended) -> DIT inv FFT, all in LDS.
// Scratch: v lives in d_ws (64MB); gate-projection scratch lives in d_out
//   (it is fully rewritten by the final GEMM).
// ---------------------------------------------------------------------------

#define TS 64
#define KS 16

// MODE 0: C = A@B + bias
// MODE 1: C = C * sigmoid(A@B + bias)     (element-wise in-place gate)
template <int MODE>
__global__ __launch_bounds__(256) void gemm_f32(
    const float* __restrict__ A, int lda,
    const float* __restrict__ B, int ldb,
    const float* __restrict__ bias,
    float* __restrict__ C, int ldc,
    int K)
{
    __shared__ float As[KS][TS + 4];  // [k][m], pitch 68 (float4-aligned)
    __shared__ float Bs[KS][TS + 4];  // [k][n]

    const int tid = threadIdx.x;
    const int tx = tid & 15;
    const int ty = tid >> 4;
    const int row0 = blockIdx.y * TS;
    const int col0 = blockIdx.x * TS;

    // cooperative load mapping
    const int am = tid >> 2;         // 0..63   (tile row)
    const int ak = (tid & 3) * 4;    // 0,4,8,12 (tile col, float4)
    const int bk = tid >> 4;         // 0..15
    const int bn = (tid & 15) * 4;   // 0..60

    float acc[4][4] = {};

    for (int k0 = 0; k0 < K; k0 += KS) {
        float4 av = *(const float4*)(A + (size_t)(row0 + am) * lda + k0 + ak);
        As[ak + 0][am] = av.x;
        As[ak + 1][am] = av.y;
        As[ak + 2][am] = av.z;
        As[ak + 3][am] = av.w;
        float4 bv = *(const float4*)(B + (size_t)(k0 + bk) * ldb + col0 + bn);
        *(float4*)&Bs[bk][bn] = bv;
        __syncthreads();
#pragma unroll
        for (int kk = 0; kk < KS; ++kk) {
            float4 a4 = *(const float4*)&As[kk][ty * 4];
            float4 b4 = *(const float4*)&Bs[kk][tx * 4];
            float ar[4] = {a4.x, a4.y, a4.z, a4.w};
            float br[4] = {b4.x, b4.y, b4.z, b4.w};
#pragma unroll
            for (int i = 0; i < 4; ++i)
#pragma unroll
                for (int j = 0; j < 4; ++j)
                    acc[i][j] = fmaf(ar[i], br[j], acc[i][j]);
        }
        __syncthreads();
    }

#pragma unroll
    for (int i = 0; i < 4; ++i) {
        float* crow = C + (size_t)(row0 + ty * 4 + i) * ldc + col0 + tx * 4;
#pragma unroll
        for (int j = 0; j < 4; ++j) {
            float val = acc[i][j] + bias[col0 + tx * 4 + j];
            if (MODE == 0) {
                crow[j] = val;
            } else {
                crow[j] = crow[j] * (1.f / (1.f + expf(-val)));
            }
        }
    }
}

// Fused rfft -> *H -> irfft per (b,d) column, in place.
// Forward DIF (natural in, bit-reversed out), multiply H at bit-reversed
// index with Hermitian extension (Im dropped at DC/Nyquist like pocketfft),
// inverse DIT (bit-reversed in, natural out). 1/4096 folded into H.
__global__ __launch_bounds__(256) void fft_filter(
    float* __restrict__ V,            // (B=4, N=4096, D=1024) in-place
    const float* __restrict__ filt)   // (D, 2049, 2) for this order
{
    __shared__ float2 S[4096];
    // bijective XCD-chunked swizzle: consecutive d land on same XCD for L2
    const int lid = blockIdx.x;                 // 4096 blocks (divisible by 8)
    const int id = (lid & 7) * 512 + (lid >> 3);
    const int b = id >> 10;
    const int d = id & 1023;
    const int tid = threadIdx.x;
    float* base = V + (size_t)b * 4096 * 1024 + d;

    for (int t = tid; t < 4096; t += 256)
        S[t] = make_float2(base[(size_t)t * 1024], 0.f);
    __syncthreads();

    // forward DIF
    for (int s = 0; s < 12; ++s) {
        const int len = 2048 >> s;
        for (int j = tid; j < 2048; j += 256) {
            const int pos = j & (len - 1);
            const int blk = j >> (11 - s);
            const int i0 = (blk << (12 - s)) + pos;
            const int i1 = i0 + len;
            float2 a = S[i0], c = S[i1];
            float2 dd = make_float2(a.x - c.x, a.y - c.y);
            S[i0] = make_float2(a.x + c.x, a.y + c.y);
            float sv, cv;
            sincospif((float)pos / (float)len, &sv, &cv);
            // dd * exp(-i*pi*pos/len) = dd * (cv - i sv)
            S[i1] = make_float2(dd.x * cv + dd.y * sv, dd.y * cv - dd.x * sv);
        }
        __syncthreads();
    }

    // pointwise spectral multiply (bit-reversed storage order)
    const float sc = 1.f / 4096.f;
    for (int p = tid; p < 4096; p += 256) {
        const int k = __brev(p) >> 20;    // 12-bit reversal
        float hr, hi;
        if (k <= 2048) {
            const float* f = filt + ((size_t)d * 2049 + k) * 2;
            hr = f[0];
            hi = (k == 0 || k == 2048) ? 0.f : f[1];
        } else {
            const float* f = filt + ((size_t)d * 2049 + (4096 - k)) * 2;
            hr = f[0];
            hi = -f[1];
        }
        float2 x = S[p];
        S[p] = make_float2((x.x * hr - x.y * hi) * sc,
                           (x.x * hi + x.y * hr) * sc);
    }
    __syncthreads();

    // inverse DIT
    for (int s = 0; s < 12; ++s) {
        const int len = 1 << s;
        for (int j = tid; j < 2048; j += 256) {
            const int pos = j & (len - 1);
            const int blk = j >> s;
            const int i0 = (blk << (s + 1)) + pos;
            const int i1 = i0 + len;
            float sv, cv;
            sincospif((float)pos / (float)len, &sv, &cv);
            float2 t = S[i1];
            // t * exp(+i*pi*pos/len)
            float2 w = make_float2(t.x * cv - t.y * sv, t.x * sv + t.y * cv);
            float2 a = S[i0];
            S[i0] = make_float2(a.x + w.x, a.y + w.y);
            S[i1] = make_float2(a.x - w.x, a.y - w.y);
        }
        __syncthreads();
    }

    for (int t = tid; t < 4096; t += 256)
        base[(size_t)t * 1024] = S[t].x;
}

extern "C" void kernel_launch(void* const* d_in, const int* in_sizes, int n_in,
                              void* d_out, int out_size, void* d_ws, size_t ws_size,
                              hipStream_t stream) {
    // input order: queries(0) keys(1) values(2) in_proj_w(3) in_proj_b(4)
    //              out_proj_w(5) out_proj_b(6) gate_w(7) gate_b(8) filters(9)
    const float* values = (const float*)d_in[2];
    const float* Win    = (const float*)d_in[3];   // (1024, 3072)
    const float* bin    = (const float*)d_in[4];   // (3072,)
    const float* Wout   = (const float*)d_in[5];   // (1024, 1024)
    const float* bout   = (const float*)d_in[6];   // (1024,)
    const float* gw     = (const float*)d_in[7];   // (2, 1024, 1024)
    const float* gb     = (const float*)d_in[8];   // (2, 1024)
    const float* filt   = (const float*)d_in[9];   // (2, 1024, 2049, 2)

    float* out = (float*)d_out;
    float* v = (float*)d_ws;       // (16384, 1024) f32 = 64 MB
    float* scr = out;              // gate-projection scratch (fully rewritten later)

    const int M = 16384, K = 1024;
    dim3 grid(1024 / TS, M / TS), blk(256);

    // proj1 -> scr
    gemm_f32<0><<<grid, blk, 0, stream>>>(values, 1024, Win + 1024, 3072, bin + 1024, scr, 1024, K);
    // proj0 (v) -> v
    gemm_f32<0><<<grid, blk, 0, stream>>>(values, 1024, Win, 3072, bin, v, 1024, K);
    // gate 0: v *= sigmoid(scr @ gw0 + gb0)
    gemm_f32<1><<<grid, blk, 0, stream>>>(scr, 1024, gw, 1024, gb, v, 1024, K);
    // filter 0 (in place on v)
    fft_filter<<<dim3(4096), blk, 0, stream>>>(v, filt);
    // proj2 -> scr
    gemm_f32<0><<<grid, blk, 0, stream>>>(values, 1024, Win + 2048, 3072, bin + 2048, scr, 1024, K);
    // gate 1
    gemm_f32<1><<<grid, blk, 0, stream>>>(scr, 1024, gw + 1024 * 1024, 1024, gb + 1024, v, 1024, K);
    // filter 1
    fft_filter<<<dim3(4096), blk, 0, stream>>>(v, filt + (size_t)1024 * 2049 * 2);
    // out = v @ Wout + bout
    gemm_f32<0><<<grid, blk, 0, stream>>>(v, 1024, Wout, 1024, bout, out, 1024, K);
}

// Round 2
// 1528.822 us; speedup vs baseline: 2.1839x; 2.1839x over previous
//
#include <hip/hip_runtime.h>
#include <hip/hip_bf16.h>
#include <math.h>

// ---------------------------------------------------------------------------
// HyenaAttention on MI355X.
// Fast path: split-bf16 (hi/lo) MFMA GEMMs + table-driven fused FFT filter.
// Fallback (ws too small): round-1 f32 GEMM path.
// ---------------------------------------------------------------------------

typedef __attribute__((ext_vector_type(8))) short      bf16x8;
typedef __attribute__((ext_vector_type(8))) unsigned short u16x8;
typedef __attribute__((ext_vector_type(4))) float      f32x4;

#define AS1 __attribute__((address_space(1)))
#define AS3 __attribute__((address_space(3)))

__device__ __forceinline__ unsigned short bf16_rne(float a) {
    unsigned u = __float_as_uint(a);
    return (unsigned short)((u + 0x7fffu + ((u >> 16) & 1u)) >> 16);
}

// ===========================================================================
// Split-bf16 MFMA GEMM.  C(16384x1024) = A(16384x1024 f32) @ Bsplit(1024x1024)
// Tile: BM=128 x BN=256 x BK=32. 256 threads = 4 waves (2x2), wave tile 64x128.
// LDS is fragment-ordered: 1KB blocks, one per (frag, plane); every
// ds_read_b128 reads a contiguous 1KB -> conflict-free.
// MODE 0: C = acc + bias ; MODE 1: C *= sigmoid(acc + bias)
// ===========================================================================
template <int MODE>
__global__ __launch_bounds__(256, 2) void gemm_split(
    const float* __restrict__ A,
    const unsigned short* __restrict__ bhi,   // (1024 n, 1024 k) bf16 bits
    const unsigned short* __restrict__ blo,
    const float* __restrict__ bias,
    float* __restrict__ C)
{
    __shared__ float4 ldsv[3072];             // 48 KB: A frags 16KB, B frags 32KB
    char* lds = (char*)ldsv;

    const int t = threadIdx.x;
    const int w = t >> 6;          // wave 0..3
    const int l = t & 63;          // lane

    // bijective XCD-chunked swizzle; chunk of 64 = 16 m-blocks x all 4 n-blocks
    const int bid = blockIdx.x;                    // 512 blocks
    const int sz  = (bid & 7) * 64 + (bid >> 3);
    const int nb  = sz & 3;
    const int mb  = sz >> 2;
    const int m0  = mb * 128;
    const int n0  = nb * 256;

    const int lr  = l & 15;        // row/col within fragment
    const int lk  = (l >> 4) * 8;  // k-offset within fragment

    // ---- staging source pointers (advance by 32 each K-step) ----
    const unsigned short* srcB[8];
#pragma unroll
    for (int i = 0; i < 8; ++i) {
        const int bi = w * 8 + i;            // 0..31
        const int g  = bi >> 1;              // n-frag 0..15
        const unsigned short* plane = (bi & 1) ? blo : bhi;
        srcB[i] = plane + (size_t)(n0 + g * 16 + lr) * 1024 + lk;
    }
    const float* srcA0 = A + (size_t)(m0 + (w    ) * 16 + lr) * 1024 + lk;
    const float* srcA1 = A + (size_t)(m0 + (w + 4) * 16 + lr) * 1024 + lk;

    f32x4 acc[4][8];
#pragma unroll
    for (int m = 0; m < 4; ++m)
#pragma unroll
        for (int g = 0; g < 8; ++g)
            acc[m][g] = (f32x4){0.f, 0.f, 0.f, 0.f};

    const int wm = w >> 1, wn = w & 1;

    for (int k0 = 0; k0 < 1024; k0 += 32) {
        // ---- B: 8 async gathers, each fills one 1KB frag block ----
#pragma unroll
        for (int i = 0; i < 8; ++i) {
            const int bi = w * 8 + i;
            __builtin_amdgcn_global_load_lds(
                (const AS1 void*)srcB[i],
                (AS3 void*)(lds + 16384 + bi * 1024), 16, 0, 0);
            srcB[i] += 32;
        }
        // ---- A: load f32, split to hi/lo bf16, write frag blocks ----
#pragma unroll
        for (int s2 = 0; s2 < 2; ++s2) {
            const int f = w + s2 * 4;                 // m-frag 0..7
            const float* asrc = s2 ? srcA1 : srcA0;
            float4 x0 = *(const float4*)asrc;
            float4 x1 = *(const float4*)(asrc + 4);
            float xs[8] = {x0.x, x0.y, x0.z, x0.w, x1.x, x1.y, x1.z, x1.w};
            u16x8 hv, lv;
#pragma unroll
            for (int j = 0; j < 8; ++j) {
                unsigned short hb = bf16_rne(xs[j]);
                float hf = __uint_as_float((unsigned)hb << 16);
                hv[j] = hb;
                lv[j] = bf16_rne(xs[j] - hf);
            }
            *(u16x8*)(lds + (f * 2 + 0) * 1024 + l * 16) = hv;
            *(u16x8*)(lds + (f * 2 + 1) * 1024 + l * 16) = lv;
        }
        srcA0 += 32; srcA1 += 32;

        __syncthreads();

        // ---- compute: 96 MFMAs / wave ----
        bf16x8 ahi[4], alo[4];
#pragma unroll
        for (int m = 0; m < 4; ++m) {
            const int f = wm * 4 + m;
            ahi[m] = *(const bf16x8*)(lds + (f * 2 + 0) * 1024 + l * 16);
            alo[m] = *(const bf16x8*)(lds + (f * 2 + 1) * 1024 + l * 16);
        }
#pragma unroll
        for (int g = 0; g < 8; ++g) {
            const int gg = wn * 8 + g;
            bf16x8 bh = *(const bf16x8*)(lds + 16384 + (gg * 2 + 0) * 1024 + l * 16);
            bf16x8 bl = *(const bf16x8*)(lds + 16384 + (gg * 2 + 1) * 1024 + l * 16);
#pragma unroll
            for (int m = 0; m < 4; ++m) {
                acc[m][g] = __builtin_amdgcn_mfma_f32_16x16x32_bf16(ahi[m], bh, acc[m][g], 0, 0, 0);
                acc[m][g] = __builtin_amdgcn_mfma_f32_16x16x32_bf16(alo[m], bh, acc[m][g], 0, 0, 0);
                acc[m][g] = __builtin_amdgcn_mfma_f32_16x16x32_bf16(ahi[m], bl, acc[m][g], 0, 0, 0);
            }
        }
        __syncthreads();
    }

    // ---- epilogue: C/D layout col=lane&15, row=(lane>>4)*4+reg ----
#pragma unroll
    for (int g = 0; g < 8; ++g) {
        const int gg  = wn * 8 + g;
        const int col = n0 + gg * 16 + lr;
        const float bg = bias[col];
#pragma unroll
        for (int m = 0; m < 4; ++m) {
            const int rowb = m0 + wm * 64 + m * 16 + (l >> 4) * 4;
#pragma unroll
            for (int r = 0; r < 4; ++r) {
                const size_t idx = (size_t)(rowb + r) * 1024 + col;
                const float val = acc[m][g][r] + bg;
                if (MODE == 0) {
                    C[idx] = val;
                } else {
                    C[idx] = C[idx] * (1.f / (1.f + expf(-val)));
                }
            }
        }
    }
}

// ===========================================================================
// Weight convert: W f32 [k=1024][n slice of 1024 at ncol0, ld] ->
// transposed bf16 hi/lo planes [n=1024][k=1024].
// grid (16,16), block 256.  Reads coalesced (256B/row); writes 32B/lane.
// ===========================================================================
__global__ __launch_bounds__(256) void wconv(
    const float* __restrict__ W, int ld, int ncol0,
    unsigned short* __restrict__ hi, unsigned short* __restrict__ lo)
{
    const int t = threadIdx.x;
    const int n  = blockIdx.x * 64 + (t & 63);
    const int kc = blockIdx.y * 64 + (t >> 6) * 16;
    float f[16];
#pragma unroll
    for (int j = 0; j < 16; ++j)
        f[j] = W[(size_t)(kc + j) * ld + ncol0 + n];
    u16x8 h0, h1, l0, l1;
#pragma unroll
    for (int j = 0; j < 8; ++j) {
        unsigned short hb = bf16_rne(f[j]);
        h0[j] = hb;
        l0[j] = bf16_rne(f[j] - __uint_as_float((unsigned)hb << 16));
        unsigned short hb2 = bf16_rne(f[j + 8]);
        h1[j] = hb2;
        l1[j] = bf16_rne(f[j + 8] - __uint_as_float((unsigned)hb2 << 16));
    }
    const size_t o = (size_t)n * 1024 + kc;
    *(u16x8*)(hi + o) = h0; *(u16x8*)(hi + o + 8) = h1;
    *(u16x8*)(lo + o) = l0; *(u16x8*)(lo + o + 8) = l1;
}

// ===========================================================================
// Fused rfft -> *H -> irfft per (b,d) column, in place.
// Packed per-stage twiddle table (len<=1024) in LDS, stride-1 reads.
// S padded i+(i>>4) to kill small-stride bank conflicts.
// ===========================================================================
__global__ __launch_bounds__(256) void fft_filter(
    float* __restrict__ V,            // (4, 4096, 1024) f32, in place
    const float* __restrict__ filt)   // (1024, 2049, 2)
{
    __shared__ float2 S[4352];        // 4096 + 256 pad
    __shared__ float2 TW[2048];       // packed: off(len) = 2048 - 2*len

    const int lid = blockIdx.x;
    const int id = (lid & 7) * 512 + (lid >> 3);   // XCD-chunked, bijective
    const int b = id >> 10;
    const int d = id & 1023;
    const int tid = threadIdx.x;
    float* base = V + ((size_t)b << 22) + d;

    // build packed twiddle table: for len in 1024..1: TW[off+j] = e^{-i pi j/len}
    {
        int off = 0;
        for (int len = 1024; len >= 1; len >>= 1) {
            for (int j = tid; j < len; j += 256) {
                float sv, cv;
                sincospif((float)j / (float)len, &sv, &cv);
                TW[off + j] = make_float2(cv, sv);
            }
            off += len;
        }
    }
    for (int t2 = tid; t2 < 4096; t2 += 256)
        S[t2 + (t2 >> 4)] = make_float2(base[(size_t)t2 << 10], 0.f);
    __syncthreads();

    // forward DIF (natural -> bit-reversed)
    for (int s = 0; s < 12; ++s) {
        const int len = 2048 >> s;
        const int off = 2048 - 2 * len;           // valid for len<=1024
        for (int j = tid; j < 2048; j += 256) {
            const int pos = j & (len - 1);
            const int blk = j >> (11 - s);
            const int i0 = (blk << (12 - s)) + pos;
            const int i1 = i0 + len;
            const int p0 = i0 + (i0 >> 4), p1 = i1 + (i1 >> 4);
            float2 a = S[p0], c = S[p1];
            float2 dd = make_float2(a.x - c.x, a.y - c.y);
            float cv, sv;
            if (len == 2048) { sincospif((float)pos / 2048.f, &sv, &cv); }
            else { float2 tw = TW[off + pos]; cv = tw.x; sv = tw.y; }
            S[p0] = make_float2(a.x + c.x, a.y + c.y);
            S[p1] = make_float2(dd.x * cv + dd.y * sv, dd.y * cv - dd.x * sv);
        }
        __syncthreads();
    }

    // spectral multiply at bit-reversed positions (pocketfft irfft semantics:
    // Im dropped at DC/Nyquist), 1/4096 folded in
    const float sc = 1.f / 4096.f;
    for (int p = tid; p < 4096; p += 256) {
        const int k = __brev(p) >> 20;
        float hr, hi2;
        if (k <= 2048) {
            const float* f = filt + ((size_t)d * 2049 + k) * 2;
            hr = f[0];
            hi2 = (k == 0 || k == 2048) ? 0.f : f[1];
        } else {
            const float* f = filt + ((size_t)d * 2049 + (4096 - k)) * 2;
            hr = f[0];
            hi2 = -f[1];
        }
        const int pp = p + (p >> 4);
        float2 x = S[pp];
        S[pp] = make_float2((x.x * hr - x.y * hi2) * sc,
                            (x.x * hi2 + x.y * hr) * sc);
    }
    __syncthreads();

    // inverse DIT (bit-reversed -> natural)
    for (int s = 0; s < 12; ++s) {
        const int len = 1 << s;
        const int off = 2048 - 2 * len;
        for (int j = tid; j < 2048; j += 256) {
            const int pos = j & (len - 1);
            const int blk = j >> s;
            const int i0 = (blk << (s + 1)) + pos;
            const int i1 = i0 + len;
            const int p0 = i0 + (i0 >> 4), p1 = i1 + (i1 >> 4);
            float cv, sv;
            if (len == 2048) { sincospif((float)pos / 2048.f, &sv, &cv); }
            else { float2 tw = TW[off + pos]; cv = tw.x; sv = tw.y; }
            float2 t2 = S[p1];
            float2 wv = make_float2(t2.x * cv - t2.y * sv, t2.x * sv + t2.y * cv);
            float2 a = S[p0];
            S[p0] = make_float2(a.x + wv.x, a.y + wv.y);
            S[p1] = make_float2(a.x - wv.x, a.y - wv.y);
        }
        __syncthreads();
    }

    for (int t2 = tid; t2 < 4096; t2 += 256)
        base[(size_t)t2 << 10] = S[t2 + (t2 >> 4)].x;
}

// ===========================================================================
// Fallback f32 GEMM (round-1, proven) for small ws_size
// ===========================================================================
#define TS 64
#define KS 16
template <int MODE>
__global__ __launch_bounds__(256) void gemm_f32(
    const float* __restrict__ A, int lda,
    const float* __restrict__ B, int ldb,
    const float* __restrict__ bias,
    float* __restrict__ C, int ldc,
    int K)
{
    __shared__ float As[KS][TS + 4];
    __shared__ float Bs[KS][TS + 4];
    const int tid = threadIdx.x;
    const int tx = tid & 15, ty = tid >> 4;
    const int row0 = blockIdx.y * TS, col0 = blockIdx.x * TS;
    const int am = tid >> 2, ak = (tid & 3) * 4;
    const int bk = tid >> 4, bn = (tid & 15) * 4;
    float acc[4][4] = {};
    for (int k0 = 0; k0 < K; k0 += KS) {
        float4 av = *(const float4*)(A + (size_t)(row0 + am) * lda + k0 + ak);
        As[ak + 0][am] = av.x; As[ak + 1][am] = av.y;
        As[ak + 2][am] = av.z; As[ak + 3][am] = av.w;
        float4 bv = *(const float4*)(B + (size_t)(k0 + bk) * ldb + col0 + bn);
        *(float4*)&Bs[bk][bn] = bv;
        __syncthreads();
#pragma unroll
        for (int kk = 0; kk < KS; ++kk) {
            float4 a4 = *(const float4*)&As[kk][ty * 4];
            float4 b4 = *(const float4*)&Bs[kk][tx * 4];
            float ar[4] = {a4.x, a4.y, a4.z, a4.w};
            float br[4] = {b4.x, b4.y, b4.z, b4.w};
#pragma unroll
            for (int i = 0; i < 4; ++i)
#pragma unroll
                for (int j = 0; j < 4; ++j)
                    acc[i][j] = fmaf(ar[i], br[j], acc[i][j]);
        }
        __syncthreads();
    }
#pragma unroll
    for (int i = 0; i < 4; ++i) {
        float* crow = C + (size_t)(row0 + ty * 4 + i) * ldc + col0 + tx * 4;
#pragma unroll
        for (int j = 0; j < 4; ++j) {
            float val = acc[i][j] + bias[col0 + tx * 4 + j];
            if (MODE == 0) crow[j] = val;
            else crow[j] = crow[j] * (1.f / (1.f + expf(-val)));
        }
    }
}

// ===========================================================================
extern "C" void kernel_launch(void* const* d_in, const int* in_sizes, int n_in,
                              void* d_out, int out_size, void* d_ws, size_t ws_size,
                              hipStream_t stream) {
    const float* values = (const float*)d_in[2];
    const float* Win    = (const float*)d_in[3];   // (1024, 3072)
    const float* bin    = (const float*)d_in[4];
    const float* Wout   = (const float*)d_in[5];   // (1024, 1024)
    const float* bout   = (const float*)d_in[6];
    const float* gw     = (const float*)d_in[7];   // (2, 1024, 1024)
    const float* gb     = (const float*)d_in[8];
    const float* filt   = (const float*)d_in[9];   // (2, 1024, 2049, 2)

    float* out = (float*)d_out;
    float* v   = (float*)d_ws;                     // 64 MB
    float* scr = out;                              // d_out doubles as scratch

    const size_t PL = (size_t)1024 * 1024;         // elems per plane
    const size_t NEED = ((size_t)64 << 20) + 12 * PL * sizeof(unsigned short);

    const size_t filt1 = (size_t)1024 * 2049 * 2;
    dim3 blk(256);

    if (ws_size >= NEED) {
        unsigned short* wp = (unsigned short*)((char*)d_ws + ((size_t)64 << 20));
        // planes: mat i -> hi = wp + i*2*PL, lo = hi + PL
        unsigned short* H[6], *L[6];
        for (int i = 0; i < 6; ++i) { H[i] = wp + (size_t)i * 2 * PL; L[i] = H[i] + PL; }

        dim3 wcg(16, 16);
        wconv<<<wcg, blk, 0, stream>>>(Win, 3072, 0,    H[0], L[0]);
        wconv<<<wcg, blk, 0, stream>>>(Win, 3072, 1024, H[1], L[1]);
        wconv<<<wcg, blk, 0, stream>>>(Win, 3072, 2048, H[2], L[2]);
        wconv<<<wcg, blk, 0, stream>>>(gw,   1024, 0,   H[3], L[3]);
        wconv<<<wcg, blk, 0, stream>>>(gw + PL, 1024, 0, H[4], L[4]);
        wconv<<<wcg, blk, 0, stream>>>(Wout, 1024, 0,   H[5], L[5]);

        gemm_split<0><<<dim3(512), blk, 0, stream>>>(values, H[1], L[1], bin + 1024, scr);
        gemm_split<0><<<dim3(512), blk, 0, stream>>>(values, H[0], L[0], bin, v);
        gemm_split<1><<<dim3(512), blk, 0, stream>>>(scr,    H[3], L[3], gb, v);
        fft_filter<<<dim3(4096), blk, 0, stream>>>(v, filt);
        gemm_split<0><<<dim3(512), blk, 0, stream>>>(values, H[2], L[2], bin + 2048, scr);
        gemm_split<1><<<dim3(512), blk, 0, stream>>>(scr,    H[4], L[4], gb + 1024, v);
        fft_filter<<<dim3(4096), blk, 0, stream>>>(v, filt + filt1);
        gemm_split<0><<<dim3(512), blk, 0, stream>>>(v,      H[5], L[5], bout, out);
    } else {
        // fallback: f32 GEMMs (round-1 path)
        const int M = 16384, K = 1024;
        dim3 grid(1024 / TS, M / TS);
        gemm_f32<0><<<grid, blk, 0, stream>>>(values, 1024, Win + 1024, 3072, bin + 1024, scr, 1024, K);
        gemm_f32<0><<<grid, blk, 0, stream>>>(values, 1024, Win, 3072, bin, v, 1024, K);
        gemm_f32<1><<<grid, blk, 0, stream>>>(scr, 1024, gw, 1024, gb, v, 1024, K);
        fft_filter<<<dim3(4096), blk, 0, stream>>>(v, filt);
        gemm_f32<0><<<grid, blk, 0, stream>>>(values, 1024, Win + 2048, 3072, bin + 2048, scr, 1024, K);
        gemm_f32<1><<<grid, blk, 0, stream>>>(scr, 1024, gw + PL, 1024, gb + 1024, v, 1024, K);
        fft_filter<<<dim3(4096), blk, 0, stream>>>(v, filt + filt1);
        gemm_f32<0><<<grid, blk, 0, stream>>>(v, 1024, Wout, 1024, bout, out, 1024, K);
    }
}

// Round 3
// 1048.163 us; speedup vs baseline: 3.1854x; 1.4586x over previous
//
#include <hip/hip_runtime.h>
#include <hip/hip_bf16.h>
#include <math.h>

// ---------------------------------------------------------------------------
// HyenaAttention on MI355X.
// GEMMs: 2-term split-bf16 MFMA (a_hi*b_hi + a_hi*b_lo).
// FFT:   pair-packed complex radix-4, fused rfft -> *H -> irfft, in LDS.
// ---------------------------------------------------------------------------

typedef __attribute__((ext_vector_type(8))) short      bf16x8;
typedef __attribute__((ext_vector_type(8))) unsigned short u16x8;
typedef __attribute__((ext_vector_type(4))) float      f32x4;

#define AS1 __attribute__((address_space(1)))
#define AS3 __attribute__((address_space(3)))

__device__ __forceinline__ unsigned short bf16_rne(float a) {
    unsigned u = __float_as_uint(a);
    return (unsigned short)((u + 0x7fffu + ((u >> 16) & 1u)) >> 16);
}
__device__ __forceinline__ float2 cmul(float2 a, float2 b) {
    return make_float2(fmaf(a.x, b.x, -a.y * b.y), fmaf(a.x, b.y, a.y * b.x));
}

// ===========================================================================
// 2-term split-bf16 MFMA GEMM. C(16384x1024) = A(f32) @ B(hi+lo bf16 planes)
// Tile BM=128 x BN=256 x BK=32, 4 waves (2x2), wave tile 64x128.
// Fragment-ordered LDS: contiguous 1KB block per (frag, plane) -> conflict-free.
// MODE 0: C = acc + bias ; MODE 1: C *= sigmoid(acc + bias)
// ===========================================================================
template <int MODE>
__global__ __launch_bounds__(256, 2) void gemm_split(
    const float* __restrict__ A,
    const unsigned short* __restrict__ bhi,   // (1024 n, 1024 k)
    const unsigned short* __restrict__ blo,
    const float* __restrict__ bias,
    float* __restrict__ C)
{
    __shared__ float4 ldsv[2560];             // 40 KB: A frags 8KB, B frags 32KB
    char* lds = (char*)ldsv;

    const int t = threadIdx.x;
    const int w = t >> 6;
    const int l = t & 63;

    const int bid = blockIdx.x;               // 512 blocks, XCD-bijective swizzle
    const int sz  = (bid & 7) * 64 + (bid >> 3);
    const int nb  = sz & 3;
    const int mb  = sz >> 2;
    const int m0  = mb * 128;
    const int n0  = nb * 256;

    const int lr  = l & 15;
    const int lk  = (l >> 4) * 8;

    const unsigned short* srcB[8];
#pragma unroll
    for (int i = 0; i < 8; ++i) {
        const int bi = w * 8 + i;             // 0..31
        const int g  = bi >> 1;               // n-frag
        const unsigned short* plane = (bi & 1) ? blo : bhi;
        srcB[i] = plane + (size_t)(n0 + g * 16 + lr) * 1024 + lk;
    }
    const float* srcA0 = A + (size_t)(m0 + (w    ) * 16 + lr) * 1024 + lk;
    const float* srcA1 = A + (size_t)(m0 + (w + 4) * 16 + lr) * 1024 + lk;

    f32x4 acc[4][8];
#pragma unroll
    for (int m = 0; m < 4; ++m)
#pragma unroll
        for (int g = 0; g < 8; ++g)
            acc[m][g] = (f32x4){0.f, 0.f, 0.f, 0.f};

    const int wm = w >> 1, wn = w & 1;

    for (int k0 = 0; k0 < 1024; k0 += 32) {
#pragma unroll
        for (int i = 0; i < 8; ++i) {
            const int bi = w * 8 + i;
            __builtin_amdgcn_global_load_lds(
                (const AS1 void*)srcB[i],
                (AS3 void*)(lds + 8192 + bi * 1024), 16, 0, 0);
            srcB[i] += 32;
        }
#pragma unroll
        for (int s2 = 0; s2 < 2; ++s2) {
            const int f = w + s2 * 4;
            const float* asrc = s2 ? srcA1 : srcA0;
            float4 x0 = *(const float4*)asrc;
            float4 x1 = *(const float4*)(asrc + 4);
            float xs[8] = {x0.x, x0.y, x0.z, x0.w, x1.x, x1.y, x1.z, x1.w};
            u16x8 hv;
#pragma unroll
            for (int j = 0; j < 8; ++j)
                hv[j] = bf16_rne(xs[j]);
            *(u16x8*)(lds + f * 1024 + l * 16) = hv;
        }
        srcA0 += 32; srcA1 += 32;

        __syncthreads();

        bf16x8 ahi[4];
#pragma unroll
        for (int m = 0; m < 4; ++m)
            ahi[m] = *(const bf16x8*)(lds + (wm * 4 + m) * 1024 + l * 16);
#pragma unroll
        for (int g = 0; g < 8; ++g) {
            const int gg = wn * 8 + g;
            bf16x8 bh = *(const bf16x8*)(lds + 8192 + (gg * 2 + 0) * 1024 + l * 16);
            bf16x8 bl = *(const bf16x8*)(lds + 8192 + (gg * 2 + 1) * 1024 + l * 16);
#pragma unroll
            for (int m = 0; m < 4; ++m) {
                acc[m][g] = __builtin_amdgcn_mfma_f32_16x16x32_bf16(ahi[m], bh, acc[m][g], 0, 0, 0);
                acc[m][g] = __builtin_amdgcn_mfma_f32_16x16x32_bf16(ahi[m], bl, acc[m][g], 0, 0, 0);
            }
        }
        __syncthreads();
    }

#pragma unroll
    for (int g = 0; g < 8; ++g) {
        const int gg  = wn * 8 + g;
        const int col = n0 + gg * 16 + lr;
        const float bg = bias[col];
#pragma unroll
        for (int m = 0; m < 4; ++m) {
            const int rowb = m0 + wm * 64 + m * 16 + (l >> 4) * 4;
#pragma unroll
            for (int r = 0; r < 4; ++r) {
                const size_t idx = (size_t)(rowb + r) * 1024 + col;
                const float val = acc[m][g][r] + bg;
                if (MODE == 0) {
                    C[idx] = val;
                } else {
                    C[idx] = C[idx] * (1.f / (1.f + expf(-val)));
                }
            }
        }
    }
}

// ===========================================================================
// Weight convert: W f32 [k][n slice] -> transposed bf16 hi/lo planes [n][k]
// ===========================================================================
__global__ __launch_bounds__(256) void wconv(
    const float* __restrict__ W, int ld, int ncol0,
    unsigned short* __restrict__ hi, unsigned short* __restrict__ lo)
{
    const int t = threadIdx.x;
    const int n  = blockIdx.x * 64 + (t & 63);
    const int kc = blockIdx.y * 64 + (t >> 6) * 16;
    float f[16];
#pragma unroll
    for (int j = 0; j < 16; ++j)
        f[j] = W[(size_t)(kc + j) * ld + ncol0 + n];
    u16x8 h0, h1, l0, l1;
#pragma unroll
    for (int j = 0; j < 8; ++j) {
        unsigned short hb = bf16_rne(f[j]);
        h0[j] = hb;
        l0[j] = bf16_rne(f[j] - __uint_as_float((unsigned)hb << 16));
        unsigned short hb2 = bf16_rne(f[j + 8]);
        h1[j] = hb2;
        l1[j] = bf16_rne(f[j + 8] - __uint_as_float((unsigned)hb2 << 16));
    }
    const size_t o = (size_t)n * 1024 + kc;
    *(u16x8*)(hi + o) = h0; *(u16x8*)(hi + o + 8) = h1;
    *(u16x8*)(lo + o) = l0; *(u16x8*)(lo + o + 8) = l1;
}

// ===========================================================================
// Pair-packed radix-4 FFT filter: columns (d, d+1) packed as z = x + i*y.
// Forward DIF (natural -> base-4-digit-reversed), Hermitian unpack + per-
// column spectral multiply (pocketfft irfft semantics: Im dropped at
// DC/Nyquist), repack, inverse DIT. Pad p(e)=e+(e>>4): all stages hit each
// bank-pair exactly 4x (b64 inherent minimum) -> conflict-free.
// ===========================================================================
__device__ __forceinline__ int dr4(int p) {   // reverse 6 base-4 digits
    int r = __brev(p) >> 20;
    return ((r & 0x555) << 1) | ((r >> 1) & 0x555);
}

__global__ __launch_bounds__(256) void fft_filter2(
    float* __restrict__ V,            // (4, 4096, 1024) f32, in place
    const float* __restrict__ filt)   // (1024, 2049, 2)
{
    __shared__ float2 S[4352];        // 4096 + 256 pad
    __shared__ float2 TW[1365];       // packed per-stage: e^{-2pi i j/(4len)}
    // offsets: len 1024->0, 256->1024, 64->1280, 16->1344, 4->1360, 1->1364

    const int lid = blockIdx.x;                    // 2048 blocks
    const int id  = (lid & 7) * 256 + (lid >> 3);  // XCD-chunked, bijective
    const int b   = id >> 9;
    const int dp  = (id & 511) * 2;
    const int tid = threadIdx.x;
    float* base = V + ((size_t)b << 22) + dp;

    {   // build twiddle tables
        int off = 0;
        for (int len = 1024; len >= 1; len >>= 2) {
            for (int j = tid; j < len; j += 256) {
                float sv, cv;
                sincospif((float)j / (2.f * (float)len), &sv, &cv);
                TW[off + j] = make_float2(cv, -sv);
            }
            off += len;
        }
    }
    for (int e = tid; e < 4096; e += 256)
        S[e + (e >> 4)] = *(const float2*)(base + ((size_t)e << 10));
    __syncthreads();

    // ---- forward radix-4 DIF ----
    {
        int off = 0;
#pragma unroll
        for (int s = 0; s < 6; ++s) {
            const int len = 1024 >> (2 * s);
            const int L = 10 - 2 * s;
#pragma unroll
            for (int u = 0; u < 4; ++u) {
                const int bf = u * 256 + tid;
                const int j  = bf & (len - 1);
                const int e0 = ((bf >> L) << (L + 2)) | j;
                const int e1 = e0 + len, e2 = e0 + 2 * len, e3 = e0 + 3 * len;
                const int p0 = e0 + (e0 >> 4), p1 = e1 + (e1 >> 4);
                const int p2 = e2 + (e2 >> 4), p3 = e3 + (e3 >> 4);
                float2 a0 = S[p0], a1 = S[p1], a2 = S[p2], a3 = S[p3];
                float2 t0 = make_float2(a0.x + a2.x, a0.y + a2.y);
                float2 t1 = make_float2(a0.x - a2.x, a0.y - a2.y);
                float2 t2 = make_float2(a1.x + a3.x, a1.y + a3.y);
                float2 t3 = make_float2(a1.x - a3.x, a1.y - a3.y);
                float2 y0 = make_float2(t0.x + t2.x, t0.y + t2.y);
                float2 y2 = make_float2(t0.x - t2.x, t0.y - t2.y);
                float2 y1 = make_float2(t1.x + t3.y, t1.y - t3.x);  // t1 - i t3
                float2 y3 = make_float2(t1.x - t3.y, t1.y + t3.x);  // t1 + i t3
                float2 w1 = TW[off + j];
                float2 w2 = cmul(w1, w1);
                float2 w3 = cmul(w2, w1);
                S[p0] = y0;
                S[p1] = cmul(y1, w1);
                S[p2] = cmul(y2, w2);
                S[p3] = cmul(y3, w3);
            }
            off += len;
            __syncthreads();
        }
    }

    // ---- Hermitian unpack, per-column filter, repack (digit-reversed) ----
    const float sc = 1.f / 4096.f;
    const float* fx = filt + (size_t)dp * 2049 * 2;
    const float* fy = filt + (size_t)(dp + 1) * 2049 * 2;
    for (int k = tid; k < 2048; k += 256) {
        if (k == 0) {
            float2 Z0 = S[0];                 // dr(0)=0, pad 0
            S[0] = make_float2(Z0.x * fx[0] * sc, Z0.y * fy[0] * sc);
            const int pn = 2;                 // dr(2048)=2
            float2 Zn = S[pn];
            S[pn] = make_float2(Zn.x * fx[2048 * 2] * sc, Zn.y * fy[2048 * 2] * sc);
        } else {
            const int q1 = dr4(k), q2 = dr4(4096 - k);
            const int pp1 = q1 + (q1 >> 4), pp2 = q2 + (q2 >> 4);
            float2 Zk = S[pp1], Zm = S[pp2];
            float2 X = make_float2(0.5f * (Zk.x + Zm.x), 0.5f * (Zk.y - Zm.y));
            float2 Y = make_float2(0.5f * (Zk.y + Zm.y), 0.5f * (Zm.x - Zk.x));
            float2 Hx = *(const float2*)(fx + 2 * k);
            float2 Hy = *(const float2*)(fy + 2 * k);
            float2 Xp = cmul(X, Hx);
            float2 Yp = cmul(Y, Hy);
            S[pp1] = make_float2((Xp.x - Yp.y) * sc, (Xp.y + Yp.x) * sc);
            S[pp2] = make_float2((Xp.x + Yp.y) * sc, (Yp.x - Xp.y) * sc);
        }
    }
    __syncthreads();

    // ---- inverse radix-4 DIT ----
    {
        int off = 1365;
#pragma unroll
        for (int s = 0; s < 6; ++s) {
            const int len = 1 << (2 * s);
            const int L = 2 * s;
            off -= len;
#pragma unroll
            for (int u = 0; u < 4; ++u) {
                const int bf = u * 256 + tid;
                const int j  = bf & (len - 1);
                const int e0 = ((bf >> L) << (L + 2)) | j;
                const int e1 = e0 + len, e2 = e0 + 2 * len, e3 = e0 + 3 * len;
                const int p0 = e0 + (e0 >> 4), p1 = e1 + (e1 >> 4);
                const int p2 = e2 + (e2 >> 4), p3 = e3 + (e3 >> 4);
                float2 w1 = TW[off + j];
                w1.y = -w1.y;                         // conj -> e^{+i}
                float2 w2 = cmul(w1, w1);
                float2 w3 = cmul(w2, w1);
                float2 x0 = S[p0];
                float2 x1 = cmul(S[p1], w1);
                float2 x2 = cmul(S[p2], w2);
                float2 x3 = cmul(S[p3], w3);
                float2 t0 = make_float2(x0.x + x2.x, x0.y + x2.y);
                float2 t1 = make_float2(x0.x - x2.x, x0.y - x2.y);
                float2 t2 = make_float2(x1.x + x3.x, x1.y + x3.y);
                float2 t3 = make_float2(x1.x - x3.x, x1.y - x3.y);
                S[p0] = make_float2(t0.x + t2.x, t0.y + t2.y);
                S[p2] = make_float2(t0.x - t2.x, t0.y - t2.y);
                S[p1] = make_float2(t1.x - t3.y, t1.y + t3.x);  // t1 + i t3
                S[p3] = make_float2(t1.x + t3.y, t1.y - t3.x);  // t1 - i t3
            }
            __syncthreads();
        }
    }

    for (int e = tid; e < 4096; e += 256)
        *(float2*)(base + ((size_t)e << 10)) = S[e + (e >> 4)];
}

// ===========================================================================
extern "C" void kernel_launch(void* const* d_in, const int* in_sizes, int n_in,
                              void* d_out, int out_size, void* d_ws, size_t ws_size,
                              hipStream_t stream) {
    const float* values = (const float*)d_in[2];
    const float* Win    = (const float*)d_in[3];   // (1024, 3072)
    const float* bin    = (const float*)d_in[4];
    const float* Wout   = (const float*)d_in[5];   // (1024, 1024)
    const float* bout   = (const float*)d_in[6];
    const float* gw     = (const float*)d_in[7];   // (2, 1024, 1024)
    const float* gb     = (const float*)d_in[8];
    const float* filt   = (const float*)d_in[9];   // (2, 1024, 2049, 2)

    float* out = (float*)d_out;
    float* v   = (float*)d_ws;                     // 64 MB
    float* scr = out;                              // d_out doubles as scratch

    const size_t PL = (size_t)1024 * 1024;
    const size_t filt1 = (size_t)1024 * 2049 * 2;
    dim3 blk(256);

    unsigned short* wp = (unsigned short*)((char*)d_ws + ((size_t)64 << 20));
    unsigned short* H[6], *L[6];
    for (int i = 0; i < 6; ++i) { H[i] = wp + (size_t)i * 2 * PL; L[i] = H[i] + PL; }

    dim3 wcg(16, 16);
    wconv<<<wcg, blk, 0, stream>>>(Win, 3072, 0,    H[0], L[0]);
    wconv<<<wcg, blk, 0, stream>>>(Win, 3072, 1024, H[1], L[1]);
    wconv<<<wcg, blk, 0, stream>>>(Win, 3072, 2048, H[2], L[2]);
    wconv<<<wcg, blk, 0, stream>>>(gw,   1024, 0,   H[3], L[3]);
    wconv<<<wcg, blk, 0, stream>>>(gw + PL, 1024, 0, H[4], L[4]);
    wconv<<<wcg, blk, 0, stream>>>(Wout, 1024, 0,   H[5], L[5]);

    gemm_split<0><<<dim3(512), blk, 0, stream>>>(values, H[1], L[1], bin + 1024, scr);
    gemm_split<0><<<dim3(512), blk, 0, stream>>>(values, H[0], L[0], bin, v);
    gemm_split<1><<<dim3(512), blk, 0, stream>>>(scr,    H[3], L[3], gb, v);
    fft_filter2<<<dim3(2048), blk, 0, stream>>>(v, filt);
    gemm_split<0><<<dim3(512), blk, 0, stream>>>(values, H[2], L[2], bin + 2048, scr);
    gemm_split<1><<<dim3(512), blk, 0, stream>>>(scr,    H[4], L[4], gb + 1024, v);
    fft_filter2<<<dim3(2048), blk, 0, stream>>>(v, filt + filt1);
    gemm_split<0><<<dim3(512), blk, 0, stream>>>(v,      H[5], L[5], bout, out);
}